// Round 2
// baseline (5227.727 us; speedup 1.0000x reference)
//
#include <hip/hip_runtime.h>
#include <math.h>

// Sizes (fixed by the problem)
#define BB 128
#define NN_ 1024
#define DD 512
#define SS 100
#define MROWS (BB*SS)            // 12800
#define TOT_CNT 6553600u         // 128*100*512

__device__ __forceinline__ unsigned rotl32(unsigned x, int r) {
    return (x << r) | (x >> (32 - r));
}

// XLA f32 erfinv (Giles polynomial) — matches jax.lax.erf_inv on f32
__device__ __forceinline__ float bits_to_normal(unsigned bits) {
    float f = __uint_as_float((bits >> 9) | 0x3F800000u) - 1.0f;  // [0,1)
    const float lo = -0.99999994f;   // nextafter(-1,0)
    float u = f * 2.0f + lo;         // (maxval-minval) rounds to exactly 2.0f
    u = fmaxf(lo, u);
    float w = -log1pf(-u * u);
    float p;
    if (w < 5.0f) {
        w -= 2.5f;
        p = 2.81022636e-08f;
        p = fmaf(p, w, 3.43273939e-07f);
        p = fmaf(p, w, -3.5233877e-06f);
        p = fmaf(p, w, -4.39150654e-06f);
        p = fmaf(p, w, 0.00021858087f);
        p = fmaf(p, w, -0.00125372503f);
        p = fmaf(p, w, -0.00417768164f);
        p = fmaf(p, w, 0.246640727f);
        p = fmaf(p, w, 1.50140941f);
    } else {
        w = sqrtf(w) - 3.0f;
        p = -0.000200214257f;
        p = fmaf(p, w, 0.000100950558f);
        p = fmaf(p, w, 0.00134934322f);
        p = fmaf(p, w, -0.00367342844f);
        p = fmaf(p, w, 0.00573950773f);
        p = fmaf(p, w, -0.0076224613f);
        p = fmaf(p, w, 0.00943887047f);
        p = fmaf(p, w, 1.00167406f);
        p = fmaf(p, w, 2.83297682f);
    }
    return 1.41421356237f * (p * u);
}

// slots = mu + |sigma| * threefry_normal(key=(0,1))
// PARTITIONABLE threefry (modern JAX default): per element e,
// (x0,x1) = threefry2x32(key, (hi32(e), lo32(e))) ; bits = x0 ^ x1.
__global__ __launch_bounds__(256)
void k_init_slots(const float* __restrict__ mu, const float* __restrict__ sigma,
                  float* __restrict__ slots) {
    unsigned e = blockIdx.x * 256u + threadIdx.x;   // < TOT_CNT
    const unsigned ks0 = 0u, ks1 = 1u, ks2 = 0x1BD11BDBu; // 0x1BD11BDA^0^1
    unsigned x0 = 0u + ks0;     // hi32(e) = 0
    unsigned x1 = e + ks1;      // lo32(e) = e
#define TF_RND(r) { x0 += x1; x1 = rotl32(x1, r); x1 ^= x0; }
    TF_RND(13) TF_RND(15) TF_RND(26) TF_RND(6)   x0 += ks1; x1 += ks2 + 1u;
    TF_RND(17) TF_RND(29) TF_RND(16) TF_RND(24)  x0 += ks2; x1 += ks0 + 2u;
    TF_RND(13) TF_RND(15) TF_RND(26) TF_RND(6)   x0 += ks0; x1 += ks1 + 3u;
    TF_RND(17) TF_RND(29) TF_RND(16) TF_RND(24)  x0 += ks1; x1 += ks2 + 4u;
    TF_RND(13) TF_RND(15) TF_RND(26) TF_RND(6)   x0 += ks2; x1 += ks0 + 5u;
#undef TF_RND
    unsigned bits = x0 ^ x1;
    int d0 = (int)(e & 511u);
    slots[e] = mu[d0] + fabsf(sigma[d0]) * bits_to_normal(bits);
}

// C[m,n] = alpha * sum_k A[m,k]*B[n,k] (+ bias[n]); A row-major lda=K, B row-major ldb=K
// 64x64 tile, BK=16, 256 threads, 4x4 microtile. Batched via blockIdx.z.
__global__ __launch_bounds__(256)
void k_gemm_nt(const float* __restrict__ A, long long strideA,
               const float* __restrict__ Bm, long long strideB,
               float* __restrict__ C, long long strideC,
               const float* __restrict__ bias,
               int M, int N, int K, float alpha) {
    __shared__ float As[16][68];
    __shared__ float Bs[16][68];
    const int tid = threadIdx.x;
    A  += (long long)blockIdx.z * strideA;
    Bm += (long long)blockIdx.z * strideB;
    C  += (long long)blockIdx.z * strideC;
    const int n0 = blockIdx.x * 64;
    const int m0 = blockIdx.y * 64;

    const int lr = tid >> 2;           // 0..63
    const int lk = (tid & 3) << 2;     // 0,4,8,12
    int arow = m0 + lr; if (arow >= M) arow = M - 1;
    const float* Ald = A  + (long long)arow * K + lk;
    const float* Bld = Bm + (long long)(n0 + lr) * K + lk;

    const int tx = tid & 15, ty = tid >> 4;
    float acc[4][4];
#pragma unroll
    for (int i = 0; i < 4; i++)
#pragma unroll
        for (int j = 0; j < 4; j++) acc[i][j] = 0.0f;

    for (int k0 = 0; k0 < K; k0 += 16) {
        float4 av = *(const float4*)(Ald + k0);
        float4 bv = *(const float4*)(Bld + k0);
        __syncthreads();
        As[lk + 0][lr] = av.x; As[lk + 1][lr] = av.y;
        As[lk + 2][lr] = av.z; As[lk + 3][lr] = av.w;
        Bs[lk + 0][lr] = bv.x; Bs[lk + 1][lr] = bv.y;
        Bs[lk + 2][lr] = bv.z; Bs[lk + 3][lr] = bv.w;
        __syncthreads();
#pragma unroll
        for (int kk = 0; kk < 16; kk++) {
            float a0[4], b0[4];
#pragma unroll
            for (int i = 0; i < 4; i++) a0[i] = As[kk][ty * 4 + i];
#pragma unroll
            for (int j = 0; j < 4; j++) b0[j] = Bs[kk][tx * 4 + j];
#pragma unroll
            for (int i = 0; i < 4; i++)
#pragma unroll
                for (int j = 0; j < 4; j++)
                    acc[i][j] = fmaf(a0[i], b0[j], acc[i][j]);
        }
    }
    const int n = n0 + tx * 4;
    float bx = 0.f, by = 0.f, bz = 0.f, bw = 0.f;
    if (bias) { bx = bias[n]; by = bias[n + 1]; bz = bias[n + 2]; bw = bias[n + 3]; }
#pragma unroll
    for (int i = 0; i < 4; i++) {
        int m = m0 + ty * 4 + i;
        if (m < M) {
            float4 o;
            o.x = acc[i][0] * alpha + bx;
            o.y = acc[i][1] * alpha + by;
            o.z = acc[i][2] * alpha + bz;
            o.w = acc[i][3] * alpha + bw;
            *(float4*)(C + (long long)m * N + n) = o;
        }
    }
}

// C[m,n] = alpha * sum_k A[m,k]*B[k,n]; A lda=K, B ldb=N. Batched via blockIdx.z.
__global__ __launch_bounds__(256)
void k_gemm_nn(const float* __restrict__ A, long long strideA,
               const float* __restrict__ Bm, long long strideB,
               float* __restrict__ C, long long strideC,
               int M, int N, int K, float alpha) {
    __shared__ float As[16][68];
    __shared__ float Bs[16][68];
    const int tid = threadIdx.x;
    A  += (long long)blockIdx.z * strideA;
    Bm += (long long)blockIdx.z * strideB;
    C  += (long long)blockIdx.z * strideC;
    const int n0 = blockIdx.x * 64;
    const int m0 = blockIdx.y * 64;

    const int lr = tid >> 2;            // 0..63
    const int lk = (tid & 3) << 2;      // A: k offset
    int arow = m0 + lr; if (arow >= M) arow = M - 1;
    const float* Ald = A + (long long)arow * K + lk;
    const int bk = tid >> 4;            // 0..15 (k row)
    const int bn = (tid & 15) << 2;     // 0..60 (n col)
    const float* Bld = Bm + (long long)bk * N + n0 + bn;

    const int tx = tid & 15, ty = tid >> 4;
    float acc[4][4];
#pragma unroll
    for (int i = 0; i < 4; i++)
#pragma unroll
        for (int j = 0; j < 4; j++) acc[i][j] = 0.0f;

    for (int k0 = 0; k0 < K; k0 += 16) {
        float4 av = *(const float4*)(Ald + k0);
        float4 bv = *(const float4*)(Bld + (long long)k0 * N);
        __syncthreads();
        As[lk + 0][lr] = av.x; As[lk + 1][lr] = av.y;
        As[lk + 2][lr] = av.z; As[lk + 3][lr] = av.w;
        *(float4*)&Bs[bk][bn] = bv;
        __syncthreads();
#pragma unroll
        for (int kk = 0; kk < 16; kk++) {
            float a0[4], b0[4];
#pragma unroll
            for (int i = 0; i < 4; i++) a0[i] = As[kk][ty * 4 + i];
#pragma unroll
            for (int j = 0; j < 4; j++) b0[j] = Bs[kk][tx * 4 + j];
#pragma unroll
            for (int i = 0; i < 4; i++)
#pragma unroll
                for (int j = 0; j < 4; j++)
                    acc[i][j] = fmaf(a0[i], b0[j], acc[i][j]);
        }
    }
#pragma unroll
    for (int i = 0; i < 4; i++) {
        int m = m0 + ty * 4 + i;
        if (m < M) {
            float4 o;
            o.x = acc[i][0] * alpha; o.y = acc[i][1] * alpha;
            o.z = acc[i][2] * alpha; o.w = acc[i][3] * alpha;
            *(float4*)(C + (long long)m * N + n0 + tx * 4) = o;
        }
    }
}

// row softmax over 1024 elements, one 256-thread block per row
__global__ __launch_bounds__(256)
void k_softmax(float* __restrict__ attn) {
    __shared__ float red[8];
    float* p = attn + (long long)blockIdx.x * 1024;
    float4 v = ((const float4*)p)[threadIdx.x];
    float mx = fmaxf(fmaxf(v.x, v.y), fmaxf(v.z, v.w));
#pragma unroll
    for (int off = 32; off; off >>= 1) mx = fmaxf(mx, __shfl_down(mx, off));
    int wid = threadIdx.x >> 6, lane = threadIdx.x & 63;
    if (lane == 0) red[wid] = mx;
    __syncthreads();
    mx = fmaxf(fmaxf(red[0], red[1]), fmaxf(red[2], red[3]));
    float e0 = expf(v.x - mx), e1 = expf(v.y - mx);
    float e2 = expf(v.z - mx), e3 = expf(v.w - mx);
    float s = (e0 + e1) + (e2 + e3);
#pragma unroll
    for (int off = 32; off; off >>= 1) s += __shfl_down(s, off);
    if (lane == 0) red[4 + wid] = s;
    __syncthreads();
    float inv = 1.0f / ((red[4] + red[5]) + (red[6] + red[7]));
    float4 o; o.x = e0 * inv; o.y = e1 * inv; o.z = e2 * inv; o.w = e3 * inv;
    ((float4*)p)[threadIdx.x] = o;
}

__device__ __forceinline__ float sigmoidf_(float x) { return 1.0f / (1.0f + expf(-x)); }

// Fused GRU: computes gi = X@Wih.T, gh = H@Whh.T for the 3 gates of a 64x64
// (row,col) tile in one pass (r/z gates accumulate ir+hr, iz+hz directly),
// then applies the pointwise cell and writes Hout. M=12800 (x64 exact), N=512.
__global__ __launch_bounds__(256)
void k_gru(const float* __restrict__ X, const float* __restrict__ H,
           const float* __restrict__ Wih, const float* __restrict__ Whh,
           const float* __restrict__ bih, const float* __restrict__ bhh,
           float* __restrict__ Hout) {
    __shared__ float Xs[16][68], Hs[16][68];
    __shared__ float Wr[16][68], Wz[16][68], Wn[16][68];
    __shared__ float Vr[16][68], Vz[16][68], Vn[16][68];
    const int tid = threadIdx.x;
    const int c0 = blockIdx.x * 64;
    const int m0 = blockIdx.y * 64;
    const int lr = tid >> 2;
    const int lk = (tid & 3) << 2;
    const float* Xld  = X   + (long long)(m0 + lr) * 512 + lk;
    const float* Hld  = H   + (long long)(m0 + lr) * 512 + lk;
    const float* Wrld = Wih + (long long)(c0 + lr) * 512 + lk;
    const float* Wzld = Wih + (long long)(512 + c0 + lr) * 512 + lk;
    const float* Wnld = Wih + (long long)(1024 + c0 + lr) * 512 + lk;
    const float* Vrld = Whh + (long long)(c0 + lr) * 512 + lk;
    const float* Vzld = Whh + (long long)(512 + c0 + lr) * 512 + lk;
    const float* Vnld = Whh + (long long)(1024 + c0 + lr) * 512 + lk;

    const int tx = tid & 15, ty = tid >> 4;
    float ar[4][4], az[4][4], ain[4][4], ahn[4][4];
#pragma unroll
    for (int i = 0; i < 4; i++)
#pragma unroll
        for (int j = 0; j < 4; j++) { ar[i][j] = az[i][j] = ain[i][j] = ahn[i][j] = 0.0f; }

    for (int k0 = 0; k0 < 512; k0 += 16) {
        float4 xv = *(const float4*)(Xld + k0);
        float4 hv = *(const float4*)(Hld + k0);
        float4 wr = *(const float4*)(Wrld + k0);
        float4 wz = *(const float4*)(Wzld + k0);
        float4 wn = *(const float4*)(Wnld + k0);
        float4 vr = *(const float4*)(Vrld + k0);
        float4 vz = *(const float4*)(Vzld + k0);
        float4 vn = *(const float4*)(Vnld + k0);
        __syncthreads();
        Xs[lk+0][lr]=xv.x; Xs[lk+1][lr]=xv.y; Xs[lk+2][lr]=xv.z; Xs[lk+3][lr]=xv.w;
        Hs[lk+0][lr]=hv.x; Hs[lk+1][lr]=hv.y; Hs[lk+2][lr]=hv.z; Hs[lk+3][lr]=hv.w;
        Wr[lk+0][lr]=wr.x; Wr[lk+1][lr]=wr.y; Wr[lk+2][lr]=wr.z; Wr[lk+3][lr]=wr.w;
        Wz[lk+0][lr]=wz.x; Wz[lk+1][lr]=wz.y; Wz[lk+2][lr]=wz.z; Wz[lk+3][lr]=wz.w;
        Wn[lk+0][lr]=wn.x; Wn[lk+1][lr]=wn.y; Wn[lk+2][lr]=wn.z; Wn[lk+3][lr]=wn.w;
        Vr[lk+0][lr]=vr.x; Vr[lk+1][lr]=vr.y; Vr[lk+2][lr]=vr.z; Vr[lk+3][lr]=vr.w;
        Vz[lk+0][lr]=vz.x; Vz[lk+1][lr]=vz.y; Vz[lk+2][lr]=vz.z; Vz[lk+3][lr]=vz.w;
        Vn[lk+0][lr]=vn.x; Vn[lk+1][lr]=vn.y; Vn[lk+2][lr]=vn.z; Vn[lk+3][lr]=vn.w;
        __syncthreads();
#pragma unroll
        for (int kk = 0; kk < 16; kk++) {
            float au[4], ah[4], br[4], bz2[4], bn2[4], cr[4], cz[4], cn[4];
#pragma unroll
            for (int i = 0; i < 4; i++) { au[i] = Xs[kk][ty*4+i]; ah[i] = Hs[kk][ty*4+i]; }
#pragma unroll
            for (int j = 0; j < 4; j++) {
                br[j] = Wr[kk][tx*4+j]; bz2[j] = Wz[kk][tx*4+j]; bn2[j] = Wn[kk][tx*4+j];
                cr[j] = Vr[kk][tx*4+j]; cz[j] = Vz[kk][tx*4+j]; cn[j] = Vn[kk][tx*4+j];
            }
#pragma unroll
            for (int i = 0; i < 4; i++)
#pragma unroll
                for (int j = 0; j < 4; j++) {
                    ar[i][j]  = fmaf(au[i], br[j],  ar[i][j]);
                    ar[i][j]  = fmaf(ah[i], cr[j],  ar[i][j]);
                    az[i][j]  = fmaf(au[i], bz2[j], az[i][j]);
                    az[i][j]  = fmaf(ah[i], cz[j],  az[i][j]);
                    ain[i][j] = fmaf(au[i], bn2[j], ain[i][j]);
                    ahn[i][j] = fmaf(ah[i], cn[j],  ahn[i][j]);
                }
        }
    }
#pragma unroll
    for (int i = 0; i < 4; i++) {
        int m = m0 + ty * 4 + i;
#pragma unroll
        for (int j = 0; j < 4; j++) {
            int c = c0 + tx * 4 + j;
            float r  = sigmoidf_(ar[i][j] + bih[c] + bhh[c]);
            float z  = sigmoidf_(az[i][j] + bih[512 + c] + bhh[512 + c]);
            float hn = ahn[i][j] + bhh[1024 + c];
            float nn = tanhf(ain[i][j] + bih[1024 + c] + r * hn);
            float hp = H[(long long)m * 512 + c];
            Hout[(long long)m * 512 + c] = (1.0f - z) * nn + z * hp;
        }
    }
}

// out[row] = sum_d updates[row, d];  out[12800] = 1/1024 (= slot_loss exactly)
__global__ __launch_bounds__(128)
void k_out(const float* __restrict__ upd, float* __restrict__ out) {
    __shared__ float r2[2];
    const float* p = upd + (long long)blockIdx.x * 512;
    float4 v = ((const float4*)p)[threadIdx.x];
    float s = (v.x + v.y) + (v.z + v.w);
#pragma unroll
    for (int off = 32; off; off >>= 1) s += __shfl_down(s, off);
    if ((threadIdx.x & 63) == 0) r2[threadIdx.x >> 6] = s;
    __syncthreads();
    if (threadIdx.x == 0) {
        out[blockIdx.x] = r2[0] + r2[1];
        if (blockIdx.x == 0) out[12800] = 0.0009765625f;  // slot_loss = 1/n
    }
}

extern "C" void kernel_launch(void* const* d_in, const int* in_sizes, int n_in,
                              void* d_out, int out_size, void* d_ws, size_t ws_size,
                              hipStream_t stream) {
    const float* inputs   = (const float*)d_in[0];
    const float* inputs_x = (const float*)d_in[1];
    const float* mu       = (const float*)d_in[2];
    const float* sigma    = (const float*)d_in[3];
    const float* to_q_w   = (const float*)d_in[4];
    const float* to_q_b   = (const float*)d_in[5];
    const float* to_k_w   = (const float*)d_in[6];
    const float* to_k_b   = (const float*)d_in[7];
    const float* w_ih     = (const float*)d_in[8];
    const float* w_hh     = (const float*)d_in[9];
    const float* b_ih     = (const float*)d_in[10];
    const float* b_hh     = (const float*)d_in[11];
    float* out = (float*)d_out;

    // ws layout (floats): k[67108864] slotsA[6553600] slotsB[6553600]
    //                     q[6553600] attn[13107200] upd[6553600]  => ~406 MB
    float* kbuf  = (float*)d_ws;
    float* slotA = kbuf  + 67108864ll;
    float* slotB = slotA + 6553600ll;
    float* qb    = slotB + 6553600ll;
    float* attn  = qb    + 6553600ll;
    float* upd   = attn  + 13107200ll;

    // slots init (partitionable JAX threefry normal)
    k_init_slots<<<25600, 256, 0, stream>>>(mu, sigma, slotA);

    // k = inputs @ to_k_w.T + to_k_b   [131072 x 512]
    k_gemm_nt<<<dim3(8, 2048, 1), 256, 0, stream>>>(
        inputs, 0, to_k_w, 0, kbuf, 0, to_k_b, 131072, 512, 512, 1.0f);

    float* cur = slotA;
    float* nxt = slotB;
    const float scale = 0.044194173824159216f;  // 512^-0.5
    for (int it = 0; it < 3; ++it) {
        // q = slots @ to_q_w.T + to_q_b   [12800 x 512]
        k_gemm_nt<<<dim3(8, 200, 1), 256, 0, stream>>>(
            cur, 0, to_q_w, 0, qb, 0, to_q_b, 12800, 512, 512, 1.0f);
        // dots = scale * q @ k^T   batched [128][100 x 1024]
        k_gemm_nt<<<dim3(16, 2, 128), 256, 0, stream>>>(
            qb, 51200ll, kbuf, 524288ll, attn, 102400ll,
            nullptr, 100, 1024, 512, scale);
        // softmax over n
        k_softmax<<<12800, 256, 0, stream>>>(attn);
        // updates = (attn @ inputs_x) / 512   batched [128][100 x 512]
        k_gemm_nn<<<dim3(8, 2, 128), 256, 0, stream>>>(
            attn, 102400ll, inputs_x, 524288ll, upd, 51200ll,
            100, 512, 1024, 0.001953125f);
        // slots = GRU(updates, slots)
        k_gru<<<dim3(8, 200, 1), 256, 0, stream>>>(
            upd, cur, w_ih, w_hh, b_ih, b_hh, nxt);
        float* t = cur; cur = nxt; nxt = t;
    }
    // out + slot_loss
    k_out<<<12800, 128, 0, stream>>>(upd, out);
}

// Round 3
// 1477.459 us; speedup vs baseline: 3.5383x; 3.5383x over previous
//
#include <hip/hip_runtime.h>
#include <math.h>

typedef __attribute__((ext_vector_type(4))) float f32x4;
typedef __attribute__((ext_vector_type(8))) short s16x8;

__device__ __forceinline__ unsigned rotl32(unsigned x, int r) {
    return (x << r) | (x >> (32 - r));
}
__device__ __forceinline__ unsigned short f2bf(float x) {
    unsigned u = __float_as_uint(x);
    unsigned r = (u + 0x7FFFu + ((u >> 16) & 1u)) >> 16;   // RNE
    return (unsigned short)r;
}
__device__ __forceinline__ float b2f(unsigned short b) {
    return __uint_as_float((unsigned)b << 16);
}
__device__ __forceinline__ void async16(const unsigned short* g, unsigned short* l) {
    __builtin_amdgcn_global_load_lds(
        (const __attribute__((address_space(1))) void*)g,
        (__attribute__((address_space(3))) void*)l, 16, 0, 0);
}

// XLA f32 erfinv (Giles polynomial)
__device__ __forceinline__ float bits_to_normal(unsigned bits) {
    float f = __uint_as_float((bits >> 9) | 0x3F800000u) - 1.0f;
    const float lo = -0.99999994f;
    float u = f * 2.0f + lo;
    u = fmaxf(lo, u);
    float w = -log1pf(-u * u);
    float p;
    if (w < 5.0f) {
        w -= 2.5f;
        p = 2.81022636e-08f;
        p = fmaf(p, w, 3.43273939e-07f);
        p = fmaf(p, w, -3.5233877e-06f);
        p = fmaf(p, w, -4.39150654e-06f);
        p = fmaf(p, w, 0.00021858087f);
        p = fmaf(p, w, -0.00125372503f);
        p = fmaf(p, w, -0.00417768164f);
        p = fmaf(p, w, 0.246640727f);
        p = fmaf(p, w, 1.50140941f);
    } else {
        w = sqrtf(w) - 3.0f;
        p = -0.000200214257f;
        p = fmaf(p, w, 0.000100950558f);
        p = fmaf(p, w, 0.00134934322f);
        p = fmaf(p, w, -0.00367342844f);
        p = fmaf(p, w, 0.00573950773f);
        p = fmaf(p, w, -0.0076224613f);
        p = fmaf(p, w, 0.00943887047f);
        p = fmaf(p, w, 1.00167406f);
        p = fmaf(p, w, 2.83297682f);
    }
    return 1.41421356237f * (p * u);
}

// slots = mu + |sigma| * threefry_normal(key=(0,1)), partitionable scheme.
__global__ __launch_bounds__(256)
void k_init_slots(const float* __restrict__ mu, const float* __restrict__ sigma,
                  float* __restrict__ slots, unsigned short* __restrict__ slotsb) {
    unsigned e = blockIdx.x * 256u + threadIdx.x;
    const unsigned ks0 = 0u, ks1 = 1u, ks2 = 0x1BD11BDBu;
    unsigned x0 = 0u + ks0;
    unsigned x1 = e + ks1;
#define TF_RND(r) { x0 += x1; x1 = rotl32(x1, r); x1 ^= x0; }
    TF_RND(13) TF_RND(15) TF_RND(26) TF_RND(6)   x0 += ks1; x1 += ks2 + 1u;
    TF_RND(17) TF_RND(29) TF_RND(16) TF_RND(24)  x0 += ks2; x1 += ks0 + 2u;
    TF_RND(13) TF_RND(15) TF_RND(26) TF_RND(6)   x0 += ks0; x1 += ks1 + 3u;
    TF_RND(17) TF_RND(29) TF_RND(16) TF_RND(24)  x0 += ks1; x1 += ks2 + 4u;
    TF_RND(13) TF_RND(15) TF_RND(26) TF_RND(6)   x0 += ks2; x1 += ks0 + 5u;
#undef TF_RND
    unsigned bits = x0 ^ x1;
    int d0 = (int)(e & 511u);
    float v = mu[d0] + fabsf(sigma[d0]) * bits_to_normal(bits);
    slots[e] = v;
    slotsb[e] = f2bf(v);
}

// flat f32 -> bf16 cast, 4 elems/thread
__global__ __launch_bounds__(256)
void k_cast(const float* __restrict__ s, unsigned short* __restrict__ d, int n4) {
    int i = blockIdx.x * 256 + threadIdx.x;
    if (i < n4) {
        float4 v = ((const float4*)s)[i];
        ((ushort4*)d)[i] = make_ushort4(f2bf(v.x), f2bf(v.y), f2bf(v.z), f2bf(v.w));
    }
}

// x [128][1024][512] f32 (b,j,d) -> xT [128][512][1024] bf16 (b,d,j)
__global__ __launch_bounds__(256)
void k_transpose_cast(const float* __restrict__ x, unsigned short* __restrict__ xT) {
    __shared__ float t[32][33];
    int b = blockIdx.z;
    int j0 = blockIdx.x * 32;
    int d0 = blockIdx.y * 32;
    int tx = threadIdx.x & 31, ty = threadIdx.x >> 5;   // ty 0..7
    const float* xp = x + ((long long)b * 1024 + j0) * 512 + d0;
#pragma unroll
    for (int q = 0; q < 4; q++) {
        int j = ty + q * 8;
        t[j][tx] = xp[(long long)j * 512 + tx];
    }
    __syncthreads();
    unsigned short* op = xT + ((long long)b * 512 + d0) * 1024 + j0;
#pragma unroll
    for (int q = 0; q < 4; q++) {
        int d = ty + q * 8;
        op[(long long)d * 1024 + tx] = f2bf(t[tx][d]);
    }
}

// C[m,n] = bf16( alpha * sum_k A[m,k]*B[n,k] (+ bias[n]) )
// A: f32 (A_F32, staged w/ in-kernel cast) or bf16 (global_load_lds x16B).
// B: bf16 [N x K] row-major (NT). 128x128 tile, BK=32, 4 waves, 16x16x32 MFMA.
template<bool A_F32, bool HAS_BIAS>
__global__ __launch_bounds__(256)
void k_mfma_nt(const void* __restrict__ Araw, long long sA,
               const unsigned short* __restrict__ B, long long sB,
               unsigned short* __restrict__ C, long long sC,
               const float* __restrict__ bias,
               int M, int N, int K, float alpha) {
    __shared__ __align__(16) unsigned short As[128 * 32];
    __shared__ __align__(16) unsigned short Bs[128 * 32];
    const int tid = threadIdx.x;
    const unsigned short* Ab = (const unsigned short*)Araw + (long long)blockIdx.z * sA;
    const float* Af = (const float*)Araw + (long long)blockIdx.z * sA;
    const unsigned short* Bb = B + (long long)blockIdx.z * sB;
    C += (long long)blockIdx.z * sC;
    const int n0 = blockIdx.x * 128;
    const int m0 = blockIdx.y * 128;

    const int lane = tid & 63;
    const int wave = tid >> 6;
    const int wm = (wave >> 1) * 64;
    const int wn = (wave & 1) * 64;
    const int lrow = lane & 15;
    const int lquad = lane >> 4;

    f32x4 acc[4][4];
#pragma unroll
    for (int i = 0; i < 4; i++)
#pragma unroll
        for (int j = 0; j < 4; j++) acc[i][j] = (f32x4)0.0f;

    // staging coords
    const int arow_s = tid >> 1;                 // A_F32: row, 2 thr/row
    const int akh_s = (tid & 1) * 16;            // A_F32: k sub-offset
    int arowg_s = m0 + arow_s; if (arowg_s >= M) arowg_s = M - 1;

    for (int k0 = 0; k0 < K; k0 += 32) {
        float4 f0, f1, f2, f3;
        if (A_F32) {
            const float* ap = Af + (long long)arowg_s * K + k0 + akh_s;
            f0 = *(const float4*)(ap);
            f1 = *(const float4*)(ap + 4);
            f2 = *(const float4*)(ap + 8);
            f3 = *(const float4*)(ap + 12);
        }
        __syncthreads();   // LDS safe to overwrite
        if (A_F32) {
            s16x8 p0, p1;
            p0[0] = (short)f2bf(f0.x); p0[1] = (short)f2bf(f0.y);
            p0[2] = (short)f2bf(f0.z); p0[3] = (short)f2bf(f0.w);
            p0[4] = (short)f2bf(f1.x); p0[5] = (short)f2bf(f1.y);
            p0[6] = (short)f2bf(f1.z); p0[7] = (short)f2bf(f1.w);
            p1[0] = (short)f2bf(f2.x); p1[1] = (short)f2bf(f2.y);
            p1[2] = (short)f2bf(f2.z); p1[3] = (short)f2bf(f2.w);
            p1[4] = (short)f2bf(f3.x); p1[5] = (short)f2bf(f3.y);
            p1[6] = (short)f2bf(f3.z); p1[7] = (short)f2bf(f3.w);
            *(s16x8*)&As[arow_s * 32 + akh_s] = p0;
            *(s16x8*)&As[arow_s * 32 + akh_s + 8] = p1;
        } else {
#pragma unroll
            for (int p = 0; p < 2; p++) {
                int c = p * 256 + tid;
                int row = c >> 2;
                int kc = (c & 3) * 8;
                int rowg = m0 + row; if (rowg >= M) rowg = M - 1;
                async16(Ab + (long long)rowg * K + k0 + kc,
                        &As[(p * 256 + (tid & ~63)) * 8]);
            }
        }
#pragma unroll
        for (int p = 0; p < 2; p++) {
            int c = p * 256 + tid;
            int row = c >> 2;
            int kc = (c & 3) * 8;
            async16(Bb + (long long)(n0 + row) * K + k0 + kc,
                    &Bs[(p * 256 + (tid & ~63)) * 8]);
        }
        __syncthreads();   // drains vmcnt (global_load_lds) + lgkmcnt

        s16x8 afr[4], bfr[4];
#pragma unroll
        for (int i = 0; i < 4; i++)
            afr[i] = *(const s16x8*)&As[(wm + i * 16 + lrow) * 32 + lquad * 8];
#pragma unroll
        for (int j = 0; j < 4; j++)
            bfr[j] = *(const s16x8*)&Bs[(wn + j * 16 + lrow) * 32 + lquad * 8];
#pragma unroll
        for (int i = 0; i < 4; i++)
#pragma unroll
            for (int j = 0; j < 4; j++)
                acc[i][j] = __builtin_amdgcn_mfma_f32_16x16x32_bf16(
                    afr[i], bfr[j], acc[i][j], 0, 0, 0);
    }

#pragma unroll
    for (int i = 0; i < 4; i++) {
#pragma unroll
        for (int r = 0; r < 4; r++) {
            int grow = m0 + wm + i * 16 + lquad * 4 + r;
            if (grow < M) {
#pragma unroll
                for (int j = 0; j < 4; j++) {
                    int gcol = n0 + wn + j * 16 + lrow;
                    float v = acc[i][j][r] * alpha;
                    if (HAS_BIAS) v += bias[gcol];
                    C[(long long)grow * N + gcol] = f2bf(v);
                }
            }
        }
    }
}

// in-place row softmax over 1024 bf16, one 256-thread block per row
__global__ __launch_bounds__(256)
void k_softmax_bf(unsigned short* __restrict__ attn) {
    __shared__ float red[8];
    unsigned short* p = attn + (long long)blockIdx.x * 1024;
    ushort4 v = ((const ushort4*)p)[threadIdx.x];
    float a0 = b2f(v.x), a1 = b2f(v.y), a2 = b2f(v.z), a3 = b2f(v.w);
    float mx = fmaxf(fmaxf(a0, a1), fmaxf(a2, a3));
#pragma unroll
    for (int off = 32; off; off >>= 1) mx = fmaxf(mx, __shfl_down(mx, off));
    int wid = threadIdx.x >> 6, lane = threadIdx.x & 63;
    if (lane == 0) red[wid] = mx;
    __syncthreads();
    mx = fmaxf(fmaxf(red[0], red[1]), fmaxf(red[2], red[3]));
    float e0 = expf(a0 - mx), e1 = expf(a1 - mx);
    float e2 = expf(a2 - mx), e3 = expf(a3 - mx);
    float s = (e0 + e1) + (e2 + e3);
#pragma unroll
    for (int off = 32; off; off >>= 1) s += __shfl_down(s, off);
    if (lane == 0) red[4 + wid] = s;
    __syncthreads();
    float inv = 1.0f / ((red[4] + red[5]) + (red[6] + red[7]));
    ((ushort4*)p)[threadIdx.x] =
        make_ushort4(f2bf(e0 * inv), f2bf(e1 * inv), f2bf(e2 * inv), f2bf(e3 * inv));
}

// GRU pointwise from bf16 gate pre-activations; slots updated in place (f32+bf16)
__global__ __launch_bounds__(256)
void k_gru_pw(const unsigned short* __restrict__ gi, const unsigned short* __restrict__ gh,
              const float* __restrict__ bih, const float* __restrict__ bhh,
              float* __restrict__ slots, unsigned short* __restrict__ slotsb) {
    long long idx = (long long)blockIdx.x * 256 + threadIdx.x;
    int m = (int)(idx >> 9);
    int c = (int)(idx & 511);
    const unsigned short* gim = gi + (long long)m * 1536;
    const unsigned short* ghm = gh + (long long)m * 1536;
    float r = 1.0f / (1.0f + expf(-(b2f(gim[c]) + b2f(ghm[c]) + bih[c] + bhh[c])));
    float z = 1.0f / (1.0f + expf(-(b2f(gim[512 + c]) + b2f(ghm[512 + c])
                                    + bih[512 + c] + bhh[512 + c])));
    float hn = b2f(ghm[1024 + c]) + bhh[1024 + c];
    float nn = tanhf(b2f(gim[1024 + c]) + bih[1024 + c] + r * hn);
    float hp = slots[idx];
    float h = (1.0f - z) * nn + z * hp;
    slots[idx] = h;
    slotsb[idx] = f2bf(h);
}

// out[row] = sum_d updb[row, d];  out[12800] = 1/1024 (slot_loss, exact)
__global__ __launch_bounds__(128)
void k_out(const unsigned short* __restrict__ updb, float* __restrict__ out) {
    __shared__ float r2[2];
    const unsigned short* p = updb + (long long)blockIdx.x * 512;
    ushort4 v = ((const ushort4*)p)[threadIdx.x];
    float s = (b2f(v.x) + b2f(v.y)) + (b2f(v.z) + b2f(v.w));
#pragma unroll
    for (int off = 32; off; off >>= 1) s += __shfl_down(s, off);
    if ((threadIdx.x & 63) == 0) r2[threadIdx.x >> 6] = s;
    __syncthreads();
    if (threadIdx.x == 0) {
        out[blockIdx.x] = r2[0] + r2[1];
        if (blockIdx.x == 0) out[12800] = 0.0009765625f;
    }
}

extern "C" void kernel_launch(void* const* d_in, const int* in_sizes, int n_in,
                              void* d_out, int out_size, void* d_ws, size_t ws_size,
                              hipStream_t stream) {
    const float* inputs   = (const float*)d_in[0];
    const float* inputs_x = (const float*)d_in[1];
    const float* mu       = (const float*)d_in[2];
    const float* sigma    = (const float*)d_in[3];
    const float* to_q_w   = (const float*)d_in[4];
    const float* to_q_b   = (const float*)d_in[5];
    const float* to_k_w   = (const float*)d_in[6];
    const float* to_k_b   = (const float*)d_in[7];
    const float* w_ih     = (const float*)d_in[8];
    const float* w_hh     = (const float*)d_in[9];
    const float* b_ih     = (const float*)d_in[10];
    const float* b_hh     = (const float*)d_in[11];
    float* out = (float*)d_out;

    // ws layout (bytes), total 403,701,760 (< 425.7 MB proven available):
    char* base = (char*)d_ws;
    unsigned short* k_bf   = (unsigned short*)(base);                 // 134,217,728
    unsigned short* xT     = (unsigned short*)(base + 134217728ll);   // 134,217,728
    float*          slots  = (float*)        (base + 268435456ll);    //  26,214,400
    unsigned short* slotsb = (unsigned short*)(base + 294649856ll);   //  13,107,200
    unsigned short* updb   = (unsigned short*)(base + 307757056ll);   //  13,107,200
    char* regionA          = base + 320864256ll;                      //  39,321,600 (q | gi)
    char* regionB          = base + 360185856ll;                      //  39,321,600 (attn | gh)
    unsigned short* Wk_bf  = (unsigned short*)(base + 399507456ll);   //     524,288
    unsigned short* Wq_bf  = (unsigned short*)(base + 400031744ll);   //     524,288
    unsigned short* Wih_bf = (unsigned short*)(base + 400556032ll);   //   1,572,864
    unsigned short* Whh_bf = (unsigned short*)(base + 402128896ll);   //   1,572,864
    unsigned short* q_bf   = (unsigned short*)regionA;
    unsigned short* gi_bf  = (unsigned short*)regionA;
    unsigned short* attnb  = (unsigned short*)regionB;
    unsigned short* gh_bf  = (unsigned short*)regionB;

    k_init_slots<<<25600, 256, 0, stream>>>(mu, sigma, slots, slotsb);
    k_cast<<<256, 256, 0, stream>>>(to_k_w, Wk_bf, 65536);
    k_cast<<<256, 256, 0, stream>>>(to_q_w, Wq_bf, 65536);
    k_cast<<<768, 256, 0, stream>>>(w_ih, Wih_bf, 196608);
    k_cast<<<768, 256, 0, stream>>>(w_hh, Whh_bf, 196608);
    k_transpose_cast<<<dim3(32, 16, 128), 256, 0, stream>>>(inputs_x, xT);

    // k = inputs @ Wk.T + bk : [131072 x 512], A fp32 staged
    k_mfma_nt<true, true><<<dim3(4, 1024, 1), 256, 0, stream>>>(
        inputs, 0, Wk_bf, 0, k_bf, 0, to_k_b, 131072, 512, 512, 1.0f);

    const float scale = 0.044194173824159216f;   // 512^-0.5
    for (int it = 0; it < 3; ++it) {
        // q = slots @ Wq.T + bq : [12800 x 512]
        k_mfma_nt<false, true><<<dim3(4, 100, 1), 256, 0, stream>>>(
            slotsb, 0, Wq_bf, 0, q_bf, 0, to_q_b, 12800, 512, 512, 1.0f);
        // dots = scale * q @ k^T : 128 x [100 x 1024]
        k_mfma_nt<false, false><<<dim3(8, 1, 128), 256, 0, stream>>>(
            q_bf, 51200, k_bf, 524288, attnb, 102400, nullptr, 100, 1024, 512, scale);
        k_softmax_bf<<<12800, 256, 0, stream>>>(attnb);
        // updates = (attn @ x) / 512 : 128 x [100 x 512] (x pre-transposed)
        k_mfma_nt<false, false><<<dim3(4, 1, 128), 256, 0, stream>>>(
            attnb, 102400, xT, 524288, updb, 51200, nullptr, 100, 512, 1024, 0.001953125f);
        // gi = upd @ Wih.T ; gh = slots @ Whh.T : [12800 x 1536]
        k_mfma_nt<false, false><<<dim3(12, 100, 1), 256, 0, stream>>>(
            updb, 0, Wih_bf, 0, gi_bf, 0, nullptr, 12800, 1536, 512, 1.0f);
        k_mfma_nt<false, false><<<dim3(12, 100, 1), 256, 0, stream>>>(
            slotsb, 0, Whh_bf, 0, gh_bf, 0, nullptr, 12800, 1536, 512, 1.0f);
        k_gru_pw<<<25600, 256, 0, stream>>>(gi_bf, gh_bf, b_ih, b_hh, slots, slotsb);
    }
    k_out<<<12800, 128, 0, stream>>>(updb, out);
}